// Round 1
// baseline (240.631 us; speedup 1.0000x reference)
//
#include <hip/hip_runtime.h>
#include <stdint.h>

#define NROWS 65536
#define HD 1024

typedef __attribute__((ext_vector_type(8))) short bf16x8;   // 8 bf16 in 4 VGPRs
typedef __attribute__((ext_vector_type(16))) float f32x16;  // MFMA 32x32 accumulator

typedef __attribute__((address_space(1))) const unsigned int* gas_ptr;
typedef __attribute__((address_space(3))) unsigned int* las_ptr;

__device__ __forceinline__ unsigned short f2bf(float f) {
  union { float f; uint32_t u; } v; v.f = f;
  uint32_t u = v.u;
  return (unsigned short)((u + 0x7fffu + ((u >> 16) & 1u)) >> 16);  // RNE
}

__device__ __forceinline__ void gl16(const void* g, void* l) {
  __builtin_amdgcn_global_load_lds((gas_ptr)g, (las_ptr)l, 16, 0, 0);
}

// ---------------- prep: W2 fp32 -> bf16, swizzled granules ----------------
// layout: W2bf[c][k], 16B granule g (=k>>3) stored at g ^ (c & 7) within row.
__global__ void k_w2bf(const float* __restrict__ W2, unsigned short* __restrict__ W2bf) {
  int i = blockIdx.x * 256 + threadIdx.x;   // 131072 threads, 1 granule each
  int c = i >> 7, g = i & 127;
  const float4* s4 = (const float4*)(W2 + (size_t)c * HD + g * 8);
  float4 a = s4[0], b = s4[1];
  uint4 pk;
  pk.x = (uint32_t)f2bf(a.x) | ((uint32_t)f2bf(a.y) << 16);
  pk.y = (uint32_t)f2bf(a.z) | ((uint32_t)f2bf(a.w) << 16);
  pk.z = (uint32_t)f2bf(b.x) | ((uint32_t)f2bf(b.y) << 16);
  pk.w = (uint32_t)f2bf(b.z) | ((uint32_t)f2bf(b.w) << 16);
  int gs = g ^ (c & 7);
  *(uint4*)(W2bf + (size_t)c * HD + gs * 8) = pk;
}

// ---------------- layer 1: h = relu(delta*W1 + b1 + (phi*oh)@Wmeta + oh@bmeta) ----------------
// h bf16 [65536][1024], same granule swizzle as W2bf (g ^= row&7).
__global__ __launch_bounds__(512) void k_layer1(
    const float* __restrict__ x, const float* __restrict__ W1,
    const float* __restrict__ b1, const float* __restrict__ Wmeta,
    const float* __restrict__ bmeta, unsigned short* __restrict__ h) {
  __shared__ float xs[128 * 12];
  int r0 = blockIdx.x * 128;
  int t = threadIdx.x;
  int j0 = t * 2;  // this thread owns output cols j0, j0+1 for 128 rows
  float w1a = W1[j0], w1b = W1[j0 + 1];
  float b1a = b1[j0], b1b = b1[j0 + 1];
  float wma[10], wmb[10], bma[10], bmb[10];
#pragma unroll
  for (int e = 0; e < 10; e++) {
    float2 wmv = *(const float2*)(Wmeta + e * HD + j0);
    float2 bmv = *(const float2*)(bmeta + e * HD + j0);
    wma[e] = wmv.x; wmb[e] = wmv.y; bma[e] = bmv.x; bmb[e] = bmv.y;
  }
  for (int i = t; i < 128 * 12; i += 512) xs[i] = x[(size_t)r0 * 12 + i];
  __syncthreads();
  for (int r = 0; r < 128; r++) {
    const float* xr = xs + r * 12;
    float delta = xr[10], phi = xr[11];
    float s1a = 0.f, s1b = 0.f, s2a = 0.f, s2b = 0.f;
#pragma unroll
    for (int e = 0; e < 10; e++) {
      float oh = xr[e];
      s1a = fmaf(oh, wma[e], s1a);
      s1b = fmaf(oh, wmb[e], s1b);
      s2a = fmaf(oh, bma[e], s2a);
      s2b = fmaf(oh, bmb[e], s2b);
    }
    float pa = fmaf(delta, w1a, b1a) + fmaf(phi, s1a, s2a);
    float pb = fmaf(delta, w1b, b1b) + fmaf(phi, s1b, s2b);
    pa = fmaxf(pa, 0.f); pb = fmaxf(pb, 0.f);
    uint32_t pk = (uint32_t)f2bf(pa) | ((uint32_t)f2bf(pb) << 16);
    int rr = r0 + r;
    int gs = (j0 >> 3) ^ (rr & 7);
    *(uint32_t*)(h + (size_t)rr * HD + gs * 8 + (j0 & 7)) = pk;
  }
}

// ---------------- layers 2+3: per-block 256x256 tile of h@W2^T, fused relu+b2, x W3 -> partials ----------------
// grid: 1024 blocks = 256 row-tiles x 4 col-tiles; 512 threads = 8 waves (2 wm x 4 wn),
// wave tile 128 rows x 64 cols as 4x2 of 32x32x16 bf16 MFMA. LDS: double-buffered
// A[256][64] + B[256][64] bf16 = 2 x 64 KiB.
__global__ __launch_bounds__(512, 2) void k_gemm(
    const unsigned short* __restrict__ h, const unsigned short* __restrict__ W2bf,
    const float* __restrict__ b2, const float* __restrict__ W3,
    float* __restrict__ partial) {
  extern __shared__ char lds[];
  int tid = threadIdx.x;
  int bx = blockIdx.x;
  int rt = bx >> 2, ct = bx & 3;
  size_t r0 = (size_t)rt * 256;
  int c0 = ct * 256;
  int w = tid >> 6, lane = tid & 63;
  int wm = w >> 2, wn = w & 3;
  int l31 = lane & 31, hi = lane >> 5;

  f32x16 acc[4][2];
#pragma unroll
  for (int rb = 0; rb < 4; rb++)
#pragma unroll
    for (int cb = 0; cb < 2; cb++)
#pragma unroll
      for (int i = 0; i < 16; i++) acc[rb][cb][i] = 0.f;

  // stage chunk t into buffer buf: A rows r0..r0+255, B rows c0..c0+255, k = t*64..+63.
  // global layouts are pre-swizzled, so a row's 64-elem chunk is 128 contiguous bytes.
  auto stage = [&](int buf, int t) {
    size_t k0 = (size_t)t * 64;
    char* lA = lds + buf * 65536;
    char* lB = lA + 32768;
#pragma unroll
    for (int q = 0; q < 4; q++) {
      int s = tid + 512 * q;          // 2048 16B segments per matrix
      int row = s >> 3, g8 = (s & 7) * 8;
      gl16(h + ((size_t)(r0 + row)) * HD + k0 + g8, lA + (size_t)s * 16);
      gl16(W2bf + ((size_t)(c0 + row)) * HD + k0 + g8, lB + (size_t)s * 16);
    }
  };

  stage(0, 0);
  __syncthreads();
  int cur = 0;
  for (int t = 0; t < 16; t++) {
    if (t + 1 < 16) stage(cur ^ 1, t + 1);
    const char* lA = lds + cur * 65536;
    const char* lB = lA + 32768;
#pragma unroll
    for (int kk = 0; kk < 4; kk++) {
      int gc = kk * 2 + hi;
      bf16x8 av[4], bv[2];
#pragma unroll
      for (int rb = 0; rb < 4; rb++) {
        int row = wm * 128 + rb * 32 + l31;
        av[rb] = *(const bf16x8*)(lA + row * 128 + ((gc ^ (row & 7)) << 4));
      }
#pragma unroll
      for (int cb = 0; cb < 2; cb++) {
        int crow = wn * 64 + cb * 32 + l31;
        bv[cb] = *(const bf16x8*)(lB + crow * 128 + ((gc ^ (crow & 7)) << 4));
      }
#pragma unroll
      for (int rb = 0; rb < 4; rb++)
#pragma unroll
        for (int cb = 0; cb < 2; cb++)
          acc[rb][cb] = __builtin_amdgcn_mfma_f32_32x32x16_bf16(av[rb], bv[cb], acc[rb][cb], 0, 0, 0);
    }
    __syncthreads();
    cur ^= 1;
  }

  // epilogue: v = relu(acc + b2[c]); out_d += v * W3[d][c]; reduce 32 lanes -> per-row pair.
  float b2c[2], w30[2], w31[2];
#pragma unroll
  for (int cb = 0; cb < 2; cb++) {
    int c = c0 + wn * 64 + cb * 32 + l31;
    b2c[cb] = b2[c];
    w30[cb] = W3[c];
    w31[cb] = W3[HD + c];
  }
  float* sOutW = (float*)lds;  // [4 wn][256 rows][2]
#pragma unroll
  for (int rb = 0; rb < 4; rb++) {
#pragma unroll
    for (int reg = 0; reg < 16; reg++) {
      float v0 = fmaxf(acc[rb][0][reg] + b2c[0], 0.f);
      float v1 = fmaxf(acc[rb][1][reg] + b2c[1], 0.f);
      float o0 = v0 * w30[0] + v1 * w30[1];
      float o1 = v0 * w31[0] + v1 * w31[1];
#pragma unroll
      for (int m = 16; m >= 1; m >>= 1) {  // masks <32: stays within each 32-lane half
        o0 += __shfl_xor(o0, m);
        o1 += __shfl_xor(o1, m);
      }
      if (l31 == 0) {
        int rowf = (reg & 3) + 8 * (reg >> 2) + 4 * hi;  // verified C/D row map (m74/m101)
        int row = wm * 128 + rb * 32 + rowf;
        sOutW[(wn * 256 + row) * 2 + 0] = o0;
        sOutW[(wn * 256 + row) * 2 + 1] = o1;
      }
    }
  }
  __syncthreads();
  {
    int i = tid;  // 512 threads, 512 values (256 rows x 2)
    float s = sOutW[i] + sOutW[512 + i] + sOutW[1024 + i] + sOutW[1536 + i];
    partial[(size_t)ct * (NROWS * 2) + r0 * 2 + i] = s;
  }
}

// ---------------- final: out = b3 + sum over 4 col-tile partials ----------------
__global__ void k_reduce(const float* __restrict__ partial, const float* __restrict__ b3,
                         float* __restrict__ out) {
  int i = blockIdx.x * 256 + threadIdx.x;  // 131072
  float s = b3[i & 1] + partial[i] + partial[131072 + i] + partial[262144 + i] + partial[393216 + i];
  out[i] = s;
}

extern "C" void kernel_launch(void* const* d_in, const int* in_sizes, int n_in,
                              void* d_out, int out_size, void* d_ws, size_t ws_size,
                              hipStream_t stream) {
  const float* x     = (const float*)d_in[0];
  const float* W1    = (const float*)d_in[1];
  const float* b1    = (const float*)d_in[2];
  const float* Wmeta = (const float*)d_in[3];
  const float* bmeta = (const float*)d_in[4];
  const float* W2    = (const float*)d_in[5];
  const float* b2    = (const float*)d_in[6];
  const float* W3    = (const float*)d_in[7];
  const float* b3    = (const float*)d_in[8];
  float* out = (float*)d_out;

  char* ws = (char*)d_ws;
  unsigned short* hbuf  = (unsigned short*)ws;                              // 128 MiB
  unsigned short* W2bf  = (unsigned short*)(ws + (size_t)NROWS * HD * 2);   // 2 MiB
  float* partial = (float*)(ws + (size_t)NROWS * HD * 2 + (size_t)HD * HD * 2);  // 2 MiB

  hipFuncSetAttribute((const void*)k_gemm, hipFuncAttributeMaxDynamicSharedMemorySize, 131072);

  k_w2bf<<<512, 256, 0, stream>>>(W2, W2bf);
  k_layer1<<<512, 512, 0, stream>>>(x, W1, b1, Wmeta, bmeta, hbuf);
  k_gemm<<<1024, 512, 131072, stream>>>(hbuf, W2bf, b2, W3, partial);
  k_reduce<<<512, 256, 0, stream>>>(partial, b3, out);
}